// Round 6
// baseline (100.937 us; speedup 1.0000x reference)
//
#include <hip/hip_runtime.h>
#include <cstdint>

#define BB 16
#define NN 65536
#define DD 32
#define KK 64
#define DELTA_V 0.5f
#define DELTA_D 1.5f

typedef short bf16x8 __attribute__((ext_vector_type(8)));
typedef float f32x16 __attribute__((ext_vector_type(16)));

__device__ __forceinline__ short f2bf(float x) {
    union { float f; unsigned u; } v; v.f = x;
    const unsigned r = v.u + 0x7FFFu + ((v.u >> 16) & 1u);  // RNE
    return (short)(r >> 16);
}

// ---------------------------------------------------------------------------
// Kernel 1: one-hot MFMA segment-sum. Lane-owns-point register loads
// (8x dwordx4 in flight = 32KB/wave MLP), per-wave LDS transpose, MFMA.
// parts[block][64][32], pcnt[block][64]: plain coalesced stores.
// ---------------------------------------------------------------------------
#define K1_BPB 64                    // blocks per batch -> grid 1024
#define K1_PPB 1024                  // points per block (4 waves x 256)
#define K1_WPTS 256                  // points per wave

__global__ __launch_bounds__(256, 4) void k_accum(
    const float* __restrict__ emb, const int* __restrict__ ids,
    const int* __restrict__ mask, float* __restrict__ parts,
    float* __restrict__ pcnt)
{
    __shared__ float tb[4][64][33];   // 33.8 KB: per-wave transpose buffers
    __shared__ float lc2[4][KK];      // 1 KB : per-wave counts
    const int tid  = threadIdx.x;
    const int w    = tid >> 6, lane = tid & 63;
    const int half = lane >> 5, d32 = lane & 31;
    const int b    = blockIdx.x >> 6;         // / K1_BPB
    const int blk  = blockIdx.x & 63;
    const size_t pw = (size_t)b * NN + (size_t)blk * K1_PPB + (size_t)w * K1_WPTS;

    f32x16 acc0 = {}, acc1 = {};
    int c0 = 0, c1 = 0;
    const int m0 = d32, m1 = d32 + 32;
    float (*T)[33] = tb[w];

    for (int s = 0; s < 4; ++s) {             // 4 stages of 64 points
        const size_t ps = pw + s * 64;
        // lane owns point ps+lane: 8 independent dwordx4 loads (128 B/lane)
        const float4* ep = (const float4*)(emb + (ps + lane) * DD);
        float4 r[8];
#pragma unroll
        for (int q = 0; q < 8; ++q) r[q] = ep[q];
        const int idr = ids[ps + lane];
        const int mkr = mask[ps + lane];
        const int vid = (mkr != 0 && (unsigned)idr < KK) ? idr : -1;

        // transpose: row-per-lane b32 writes, bank=(lane+j)&31 -> conflict-free
        float* myrow = T[lane];
#pragma unroll
        for (int q = 0; q < 8; ++q) {
            myrow[4 * q + 0] = r[q].x; myrow[4 * q + 1] = r[q].y;
            myrow[4 * q + 2] = r[q].z; myrow[4 * q + 3] = r[q].w;
        }

#pragma unroll
        for (int q = 0; q < 4; ++q) {         // 16-point MFMA pairs
            bf16x8 bfB, a0, a1;
#pragma unroll
            for (int e = 0; e < 8; ++e) {
                bfB[e] = f2bf(T[q * 16 + 8 * half + e][d32]);
                const int s_lo = __builtin_amdgcn_readlane(vid, q * 16 + e);
                const int s_hi = __builtin_amdgcn_readlane(vid, q * 16 + 8 + e);
                const int sel  = half ? s_hi : s_lo;
                const bool h0 = (sel == m0), h1 = (sel == m1);
                a0[e] = h0 ? (short)0x3F80 : (short)0;   // bf16 1.0
                a1[e] = h1 ? (short)0x3F80 : (short)0;
                c0 += h0 ? 1 : 0;
                c1 += h1 ? 1 : 0;
            }
            acc0 = __builtin_amdgcn_mfma_f32_32x32x16_bf16(a0, bfB, acc0, 0, 0, 0);
            acc1 = __builtin_amdgcn_mfma_f32_32x32x16_bf16(a1, bfB, acc1, 0, 0, 0);
        }
    }
    __syncthreads();                          // done with tb as transpose buf

    // park C fragments in tb[w] (verified C/D layout), reduce 4 waves
#pragma unroll
    for (int r = 0; r < 16; ++r) {
        const int mrow = (r & 3) + 8 * (r >> 2) + 4 * half;
        T[mrow][d32]      = acc0[r];
        T[32 + mrow][d32] = acc1[r];
    }
    c0 += __shfl_down(c0, 32);
    c1 += __shfl_down(c1, 32);
    if (lane < 32) { lc2[w][lane] = (float)c0; lc2[w][lane + 32] = (float)c1; }
    __syncthreads();

    float* pb = parts + (size_t)blockIdx.x * (KK * DD);
    for (int i = tid; i < KK * DD; i += 256) {
        const int row = i >> 5, col = i & 31;
        pb[i] = tb[0][row][col] + tb[1][row][col] + tb[2][row][col] + tb[3][row][col];
    }
    if (tid < KK)
        pcnt[(size_t)blockIdx.x * KK + tid] =
            lc2[0][tid] + lc2[1][tid] + lc2[2][tid] + lc2[3][tid];
}

// ---------------------------------------------------------------------------
// Kernel 2: fold 64 partials/batch -> mu[b][k][33] (col 32 = count),
// then (same block) per-batch reg loss + pairwise push loss.
// ---------------------------------------------------------------------------
__global__ __launch_bounds__(256) void k_reduce_push(
    const float* __restrict__ parts, const float* __restrict__ pcnt,
    float* __restrict__ mu, float* __restrict__ regb,
    float* __restrict__ distb)
{
    const int b = blockIdx.x;
    const int tid = threadIdx.x;
    __shared__ float lm[KK][DD + 1];
    __shared__ float lcnt[KK];
    __shared__ float red[4];

    // counts
    if (tid < KK) {
        float s = 0.f;
        for (int j = 0; j < K1_BPB; ++j)
            s += pcnt[((size_t)b * K1_BPB + j) * KK + tid];
        lcnt[tid] = s;
        mu[(size_t)b * KK * 33 + tid * 33 + 32] = s;
    }
    __syncthreads();

    // sums -> means
    for (int e = tid; e < KK * DD; e += 256) {
        float s = 0.f;
        for (int j = 0; j < K1_BPB; ++j)
            s += parts[((size_t)b * K1_BPB + j) * (KK * DD) + e];
        const int k = e >> 5, d = e & 31;
        const float m = s / fmaxf(lcnt[k], 1.f);
        lm[k][d] = m;
        mu[(size_t)b * KK * 33 + k * 33 + d] = m;
    }
    __syncthreads();

    // reg loss + num_inst
    float ninst = 0.f;
    if (tid < KK) {
        const float c = lcnt[tid];
        const float pres = (c > 0.f) ? 1.f : 0.f;
        float sq = 0.f;
#pragma unroll
        for (int d = 0; d < DD; ++d) { const float m = lm[tid][d]; sq = fmaf(m, m, sq); }
        float nm = ((sq > 0.f) ? sqrtf(sq) : 0.f) * pres;
        float pn = pres;
        for (int off = 32; off; off >>= 1) {
            pn += __shfl_down(pn, off);
            nm += __shfl_down(nm, off);
        }
        if (tid == 0) {
            ninst = pn;
            regb[b] = nm / fmaxf(pn, 1.f);
        }
    }

    // pairwise push loss
    float acc = 0.f;
    for (int idx = tid; idx < KK * KK; idx += 256) {
        const int i = idx >> 6, j = idx & 63;
        if (i < j && lcnt[i] > 0.f && lcnt[j] > 0.f) {
            float dsq = 0.f;
#pragma unroll
            for (int d = 0; d < DD; ++d) {
                const float df = lm[i][d] - lm[j][d];
                dsq = fmaf(df, df, dsq);
            }
            const float pd = (dsq > 0.f) ? sqrtf(dsq) : 0.f;
            const float pen = fmaxf(2.f * DELTA_D - pd, 0.f);
            acc = fmaf(pen, pen, acc);
        }
    }
    for (int off = 32; off; off >>= 1) acc += __shfl_down(acc, off);
    if ((tid & 63) == 0) red[tid >> 6] = acc;
    __syncthreads();
    if (tid == 0) {
        const float tot = red[0] + red[1] + red[2] + red[3];
        const float np = ninst * (ninst - 1.f) * 0.5f;
        distb[b] = tot / fmaxf(np, 1.f);
    }
}

// ---------------------------------------------------------------------------
// Kernel 3: pull (variance) pass. pen^2/count folded per point; per-block
// partial written plain (no atomics, no memset needed).
// ---------------------------------------------------------------------------
#define K2_BPB 64
#define K2_PTS (NN / K2_BPB)             // 1024

__global__ __launch_bounds__(256) void k_pull(
    const float* __restrict__ emb, const int* __restrict__ ids,
    const int* __restrict__ mask, const float* __restrict__ mu,
    float* __restrict__ varpart)
{
    __shared__ float smu[KK * 33];
    __shared__ float red[4];
    const int tid = threadIdx.x;
    const int b   = blockIdx.x >> 6;
    const int blk = blockIdx.x & 63;

    const float* mub = mu + (size_t)b * KK * 33;
    for (int i = tid; i < KK * 33; i += 256) smu[i] = mub[i];
    __syncthreads();

    const size_t p0 = (size_t)b * NN + (size_t)blk * K2_PTS;
    float accv = 0.f;
    for (int p = tid; p < K2_PTS; p += 256) {
        const int id = ids[p0 + p];
        const bool v = (mask[p0 + p] != 0) && ((unsigned)id < KK);
        const int sid = v ? id : 0;
        const float* mr = smu + sid * 33;
        const float4* e = (const float4*)(emb + (p0 + p) * DD);
        float dsq = 0.f;
#pragma unroll
        for (int q = 0; q < 8; ++q) {
            const float4 t = e[q];
            float a;
            a = t.x - mr[4 * q + 0]; dsq = fmaf(a, a, dsq);
            a = t.y - mr[4 * q + 1]; dsq = fmaf(a, a, dsq);
            a = t.z - mr[4 * q + 2]; dsq = fmaf(a, a, dsq);
            a = t.w - mr[4 * q + 3]; dsq = fmaf(a, a, dsq);
        }
        const float dist = (dsq > 0.f) ? sqrtf(dsq) : 0.f;
        float pen = fmaxf(dist - DELTA_V, 0.f);
        pen = pen * pen;
        if (v) accv += pen / fmaxf(mr[32], 1.f);
    }
    for (int off = 32; off; off >>= 1) accv += __shfl_down(accv, off);
    if ((tid & 63) == 0) red[tid >> 6] = accv;
    __syncthreads();
    if (tid == 0)
        varpart[blockIdx.x] = red[0] + red[1] + red[2] + red[3];
}

// ---------------------------------------------------------------------------
// Kernel 4: final combine -> 4 outputs
// ---------------------------------------------------------------------------
__global__ __launch_bounds__(64) void k_final(
    const float* __restrict__ mu, const float* __restrict__ varpart,
    const float* __restrict__ regb, const float* __restrict__ distb,
    float* __restrict__ out)
{
    const int tid = threadIdx.x;
    __shared__ float s_var[BB], s_valid[BB];
    if (tid < BB) {
        const int b = tid;
        float ni = 0.f;
        for (int k = 0; k < KK; ++k)
            ni += (mu[(size_t)b * KK * 33 + k * 33 + 32] > 0.f) ? 1.f : 0.f;
        float vs = 0.f;
        for (int j = 0; j < K2_BPB; ++j) vs += varpart[b * K2_BPB + j];
        s_var[tid]   = vs / fmaxf(ni, 1.f);
        s_valid[tid] = (ni >= 2.f) ? 1.f : 0.f;
    }
    __syncthreads();
    if (tid == 0) {
        float denom = 0.f, v = 0.f, d = 0.f, r = 0.f;
        for (int b = 0; b < BB; ++b) {
            const float vb = s_valid[b];
            denom += vb;
            v += s_var[b] * vb;
            d += distb[b] * vb;
            r += regb[b] * vb;
        }
        denom = fmaxf(denom, 1.f);
        v /= denom; d /= denom; r /= denom;
        out[0] = v + d + 0.001f * r;   // ALPHA=BETA=1, GAMMA=0.001
        out[1] = v;
        out[2] = d;
        out[3] = r;
    }
}

// ---------------------------------------------------------------------------
extern "C" void kernel_launch(void* const* d_in, const int* in_sizes, int n_in,
                              void* d_out, int out_size, void* d_ws, size_t ws_size,
                              hipStream_t stream)
{
    const float* emb  = (const float*)d_in[0];
    const int*   ids  = (const int*)d_in[1];
    const int*   mask = (const int*)d_in[2];   // bool widened to int32

    float* ws      = (float*)d_ws;
    float* parts   = ws;                                        // 1024*2048
    float* pcnt    = parts + (size_t)BB * K1_BPB * KK * DD;     // 1024*64
    float* mu      = pcnt + (size_t)BB * K1_BPB * KK;           // 16*64*33
    float* varpart = mu + (size_t)BB * KK * 33;                 // 1024
    float* regb    = varpart + BB * K2_BPB;                     // 16
    float* distb   = regb + BB;                                 // 16

    k_accum<<<BB * K1_BPB, 256, 0, stream>>>(emb, ids, mask, parts, pcnt);
    k_reduce_push<<<BB, 256, 0, stream>>>(parts, pcnt, mu, regb, distb);
    k_pull<<<BB * K2_BPB, 256, 0, stream>>>(emb, ids, mask, mu, varpart);
    k_final<<<1, 64, 0, stream>>>(mu, varpart, regb, distb, (float*)d_out);
}

// Round 7
// 96.035 us; speedup vs baseline: 1.0510x; 1.0510x over previous
//
#include <hip/hip_runtime.h>
#include <cstdint>

#define BB 16
#define NN 65536
#define DD 32
#define KK 64
#define DELTA_V 0.5f
#define DELTA_D 1.5f

typedef short bf16x8 __attribute__((ext_vector_type(8)));
typedef float f32x16 __attribute__((ext_vector_type(16)));

__device__ __forceinline__ short f2bf(float x) {
    union { float f; unsigned u; } v; v.f = x;
    const unsigned r = v.u + 0x7FFFu + ((v.u >> 16) & 1u);  // RNE
    return (short)(r >> 16);
}

// ---------------------------------------------------------------------------
// Kernel 1: one-hot MFMA segment-sum, FULLY COALESCED loads.
// Wave stage = 64 points (8KB) via 8 contiguous 1KB dwordx4 instructions;
// lane l carries point i*8+l/8, dims (l%8)*4..+3 -> ds_write_b128 transpose.
// ---------------------------------------------------------------------------
#define K1_BPB 64                    // blocks per batch -> grid 1024
#define K1_PPB 1024                  // points per block (4 waves x 256)

__global__ __launch_bounds__(256, 4) void k_accum(
    const float* __restrict__ emb, const int* __restrict__ ids,
    const int* __restrict__ mask, float* __restrict__ parts,
    float* __restrict__ pcnt)
{
    __shared__ float tb[4][64][36];   // 36 KB: per-wave transpose buffers
    __shared__ float lc2[4][KK];      // 1 KB : per-wave counts
    const int tid  = threadIdx.x;
    const int w    = tid >> 6, lane = tid & 63;
    const int half = lane >> 5, d32 = lane & 31;
    const int pl   = lane >> 3;       // 0..7  point-within-chunk
    const int pc   = lane & 7;        // 0..7  dim chunk
    const int b    = blockIdx.x >> 6;
    const int blk  = blockIdx.x & 63;
    const size_t pw = (size_t)b * NN + (size_t)blk * K1_PPB + (size_t)w * 256;

    f32x16 acc0 = {}, acc1 = {};
    int c0 = 0, c1 = 0;
    const int m0 = d32, m1 = d32 + 32;
    float (*T)[36] = tb[w];

    for (int s = 0; s < 4; ++s) {             // 4 stages of 64 points
        const size_t ps = pw + s * 64;
        const float4* ep4 = (const float4*)(emb + ps * DD);
        float4 r[8];
#pragma unroll
        for (int i = 0; i < 8; ++i) r[i] = ep4[i * 64 + lane];  // contiguous 1KB
        const int idr = ids[ps + lane];
        const int mkr = mask[ps + lane];
        const int vid = (mkr != 0 && (unsigned)idr < KK) ? idr : -1;

        // transpose: lane writes its float4 to T[point][4*pc], aligned b128
#pragma unroll
        for (int i = 0; i < 8; ++i)
            *(float4*)&T[i * 8 + pl][4 * pc] = r[i];

#pragma unroll
        for (int q = 0; q < 4; ++q) {         // 16-point MFMA pairs
            bf16x8 bfB, a0, a1;
#pragma unroll
            for (int e = 0; e < 8; ++e) {
                bfB[e] = f2bf(T[q * 16 + 8 * half + e][d32]);
                const int s_lo = __builtin_amdgcn_readlane(vid, q * 16 + e);
                const int s_hi = __builtin_amdgcn_readlane(vid, q * 16 + 8 + e);
                const int sel  = half ? s_hi : s_lo;
                const bool h0 = (sel == m0), h1 = (sel == m1);
                a0[e] = h0 ? (short)0x3F80 : (short)0;   // bf16 1.0
                a1[e] = h1 ? (short)0x3F80 : (short)0;
                c0 += h0 ? 1 : 0;
                c1 += h1 ? 1 : 0;
            }
            acc0 = __builtin_amdgcn_mfma_f32_32x32x16_bf16(a0, bfB, acc0, 0, 0, 0);
            acc1 = __builtin_amdgcn_mfma_f32_32x32x16_bf16(a1, bfB, acc1, 0, 0, 0);
        }
    }

    // park C fragments in T (verified C/D layout), reduce 4 waves after sync
#pragma unroll
    for (int r = 0; r < 16; ++r) {
        const int mrow = (r & 3) + 8 * (r >> 2) + 4 * half;
        T[mrow][d32]      = acc0[r];
        T[32 + mrow][d32] = acc1[r];
    }
    c0 += __shfl_down(c0, 32);
    c1 += __shfl_down(c1, 32);
    if (lane < 32) { lc2[w][lane] = (float)c0; lc2[w][lane + 32] = (float)c1; }
    __syncthreads();

    float* pb = parts + (size_t)blockIdx.x * (KK * DD);
    for (int i = tid; i < KK * DD; i += 256) {
        const int row = i >> 5, col = i & 31;
        pb[i] = tb[0][row][col] + tb[1][row][col] + tb[2][row][col] + tb[3][row][col];
    }
    if (tid < KK)
        pcnt[(size_t)blockIdx.x * KK + tid] =
            lc2[0][tid] + lc2[1][tid] + lc2[2][tid] + lc2[3][tid];
}

// ---------------------------------------------------------------------------
// Kernel 2: fold 64 partials/batch -> mu[b][k][36] (d:0-31, 32=count,
// 33=1/max(count,1)), then per-batch reg loss + pairwise push loss.
// ---------------------------------------------------------------------------
__global__ __launch_bounds__(256) void k_reduce_push(
    const float* __restrict__ parts, const float* __restrict__ pcnt,
    float* __restrict__ mu, float* __restrict__ regb,
    float* __restrict__ distb)
{
    const int b = blockIdx.x;
    const int tid = threadIdx.x;
    __shared__ float lm[KK][DD + 1];
    __shared__ float lcnt[KK];
    __shared__ float red[4];

    if (tid < KK) {
        float s = 0.f;
        for (int j = 0; j < K1_BPB; ++j)
            s += pcnt[((size_t)b * K1_BPB + j) * KK + tid];
        lcnt[tid] = s;
        mu[(size_t)b * KK * 36 + tid * 36 + 32] = s;
        mu[(size_t)b * KK * 36 + tid * 36 + 33] = 1.f / fmaxf(s, 1.f);
    }
    __syncthreads();

    for (int e = tid; e < KK * DD; e += 256) {
        float s = 0.f;
        for (int j = 0; j < K1_BPB; ++j)
            s += parts[((size_t)b * K1_BPB + j) * (KK * DD) + e];
        const int k = e >> 5, d = e & 31;
        const float m = s / fmaxf(lcnt[k], 1.f);
        lm[k][d] = m;
        mu[(size_t)b * KK * 36 + k * 36 + d] = m;
    }
    __syncthreads();

    float ninst = 0.f;
    if (tid < KK) {
        const float c = lcnt[tid];
        const float pres = (c > 0.f) ? 1.f : 0.f;
        float sq = 0.f;
#pragma unroll
        for (int d = 0; d < DD; ++d) { const float m = lm[tid][d]; sq = fmaf(m, m, sq); }
        float nm = ((sq > 0.f) ? sqrtf(sq) : 0.f) * pres;
        float pn = pres;
        for (int off = 32; off; off >>= 1) {
            pn += __shfl_down(pn, off);
            nm += __shfl_down(nm, off);
        }
        if (tid == 0) {
            ninst = pn;
            regb[b] = nm / fmaxf(pn, 1.f);
        }
    }

    float acc = 0.f;
    for (int idx = tid; idx < KK * KK; idx += 256) {
        const int i = idx >> 6, j = idx & 63;
        if (i < j && lcnt[i] > 0.f && lcnt[j] > 0.f) {
            float dsq = 0.f;
#pragma unroll
            for (int d = 0; d < DD; ++d) {
                const float df = lm[i][d] - lm[j][d];
                dsq = fmaf(df, df, dsq);
            }
            const float pd = (dsq > 0.f) ? sqrtf(dsq) : 0.f;
            const float pen = fmaxf(2.f * DELTA_D - pd, 0.f);
            acc = fmaf(pen, pen, acc);
        }
    }
    for (int off = 32; off; off >>= 1) acc += __shfl_down(acc, off);
    if ((tid & 63) == 0) red[tid >> 6] = acc;
    __syncthreads();
    if (tid == 0) {
        const float tot = red[0] + red[1] + red[2] + red[3];
        const float np = ninst * (ninst - 1.f) * 0.5f;
        distb[b] = tot / fmaxf(np, 1.f);
    }
}

// ---------------------------------------------------------------------------
// Kernel 3: pull (variance) pass, FULLY COALESCED. 8 points/instruction;
// dsq reduced over the 8 dim-lanes via shfl_xor; per-block partial out.
// ---------------------------------------------------------------------------
#define K2_BPB 64
#define K2_PTS 1024

__global__ __launch_bounds__(256) void k_pull(
    const float* __restrict__ emb, const int* __restrict__ ids,
    const int* __restrict__ mask, const float* __restrict__ mu,
    float* __restrict__ varpart)
{
    __shared__ float smu[KK][36];
    __shared__ float red[4];
    const int tid = threadIdx.x;
    const int w = tid >> 6, lane = tid & 63;
    const int pl = lane >> 3;       // point-within-8
    const int pc = lane & 7;        // dim chunk
    const int b   = blockIdx.x >> 6;
    const int blk = blockIdx.x & 63;

    const float* mub = mu + (size_t)b * KK * 36;
    for (int i = tid; i < KK * 36; i += 256) ((float*)smu)[i] = mub[i];
    __syncthreads();

    const size_t p0 = (size_t)b * NN + (size_t)blk * K2_PTS + (size_t)w * 256;
    float accv = 0.f;
    for (int t = 0; t < 4; ++t) {             // 64-point tiles
        const size_t pt0 = p0 + t * 64;
        const int idr = ids[pt0 + lane];
        const int mkr = mask[pt0 + lane];
        const int vid = (mkr != 0 && (unsigned)idr < KK) ? idr : -1;
        const float4* ep4 = (const float4*)(emb + pt0 * DD);
#pragma unroll
        for (int g = 0; g < 8; ++g) {         // 8 points per group
            const float4 x = ep4[g * 64 + lane];          // contiguous 1KB
            const int sid = __shfl(vid, g * 8 + pl);      // my point's id
            const int row = (sid >= 0) ? sid : 0;
            const float4 m4 = *(const float4*)&smu[row][4 * pc];
            float dsq;
            {
                float a = x.x - m4.x; dsq = a * a;
                a = x.y - m4.y; dsq = fmaf(a, a, dsq);
                a = x.z - m4.z; dsq = fmaf(a, a, dsq);
                a = x.w - m4.w; dsq = fmaf(a, a, dsq);
            }
            dsq += __shfl_xor(dsq, 1);
            dsq += __shfl_xor(dsq, 2);
            dsq += __shfl_xor(dsq, 4);
            if (pc == 0 && sid >= 0) {
                const float dist = (dsq > 0.f) ? sqrtf(dsq) : 0.f;
                float pen = fmaxf(dist - DELTA_V, 0.f);
                accv = fmaf(pen * pen, smu[row][33], accv);   // *1/max(cnt,1)
            }
        }
    }
    for (int off = 32; off; off >>= 1) accv += __shfl_down(accv, off);
    if (lane == 0) red[w] = accv;
    __syncthreads();
    if (tid == 0)
        varpart[blockIdx.x] = red[0] + red[1] + red[2] + red[3];
}

// ---------------------------------------------------------------------------
// Kernel 4: final combine -> 4 outputs
// ---------------------------------------------------------------------------
__global__ __launch_bounds__(64) void k_final(
    const float* __restrict__ mu, const float* __restrict__ varpart,
    const float* __restrict__ regb, const float* __restrict__ distb,
    float* __restrict__ out)
{
    const int tid = threadIdx.x;
    __shared__ float s_var[BB], s_valid[BB];
    if (tid < BB) {
        const int b = tid;
        float ni = 0.f;
        for (int k = 0; k < KK; ++k)
            ni += (mu[(size_t)b * KK * 36 + k * 36 + 32] > 0.f) ? 1.f : 0.f;
        float vs = 0.f;
        for (int j = 0; j < K2_BPB; ++j) vs += varpart[b * K2_BPB + j];
        s_var[tid]   = vs / fmaxf(ni, 1.f);
        s_valid[tid] = (ni >= 2.f) ? 1.f : 0.f;
    }
    __syncthreads();
    if (tid == 0) {
        float denom = 0.f, v = 0.f, d = 0.f, r = 0.f;
        for (int b = 0; b < BB; ++b) {
            const float vb = s_valid[b];
            denom += vb;
            v += s_var[b] * vb;
            d += distb[b] * vb;
            r += regb[b] * vb;
        }
        denom = fmaxf(denom, 1.f);
        v /= denom; d /= denom; r /= denom;
        out[0] = v + d + 0.001f * r;   // ALPHA=BETA=1, GAMMA=0.001
        out[1] = v;
        out[2] = d;
        out[3] = r;
    }
}

// ---------------------------------------------------------------------------
extern "C" void kernel_launch(void* const* d_in, const int* in_sizes, int n_in,
                              void* d_out, int out_size, void* d_ws, size_t ws_size,
                              hipStream_t stream)
{
    const float* emb  = (const float*)d_in[0];
    const int*   ids  = (const int*)d_in[1];
    const int*   mask = (const int*)d_in[2];   // bool widened to int32

    float* ws      = (float*)d_ws;
    float* parts   = ws;                                        // 1024*2048
    float* pcnt    = parts + (size_t)BB * K1_BPB * KK * DD;     // 1024*64
    float* mu      = pcnt + (size_t)BB * K1_BPB * KK;           // 16*64*36
    float* varpart = mu + (size_t)BB * KK * 36;                 // 1024
    float* regb    = varpart + BB * K2_BPB;                     // 16
    float* distb   = regb + BB;                                 // 16

    k_accum<<<BB * K1_BPB, 256, 0, stream>>>(emb, ids, mask, parts, pcnt);
    k_reduce_push<<<BB, 256, 0, stream>>>(parts, pcnt, mu, regb, distb);
    k_pull<<<BB * K2_BPB, 256, 0, stream>>>(emb, ids, mask, mu, varpart);
    k_final<<<1, 64, 0, stream>>>(mu, varpart, regb, distb, (float*)d_out);
}